// Round 3
// baseline (613.172 us; speedup 1.0000x reference)
//
#include <hip/hip_runtime.h>
#include <hip/hip_bf16.h>
#include <hip/hip_fp16.h>

#define E_EDGES   800000
#define NN_NODES  50000
#define NODE_DIM  128
#define EDGE_DIM  64
#define KDIM      320
#define NTOT      256      // val(128) || gate(128)
#define BM        128      // edges per block
#define BK        64       // K chunk
#define SA        72       // padded LDS row stride in f16 elems (144 B = 36 dwords)
#define THREADS   512

typedef _Float16 half8 __attribute__((ext_vector_type(8)));
typedef float    f32x4 __attribute__((ext_vector_type(4)));

__device__ __forceinline__ unsigned short f2h(float f) {
    _Float16 h = (_Float16)f;
    return __builtin_bit_cast(unsigned short, h);
}

// ---- cast x (N_NODES x 128) and W_val||W_mul (256 x 320) fp32 -> f16, one launch ----
__global__ void cast_all_kernel(const float* __restrict__ x,
                                const float* __restrict__ wv,
                                const float* __restrict__ wm,
                                unsigned short* __restrict__ xh,
                                unsigned short* __restrict__ wc) {
    const int n4x = (NN_NODES * NODE_DIM) / 4;        // 1,600,000
    const int n4h = (NODE_DIM * KDIM) / 4;            // 10,240
    int i = blockIdx.x * blockDim.x + threadIdx.x;
    if (i < n4x) {
        float4 f = ((const float4*)x)[i];
        ushort4 o;
        o.x = f2h(f.x); o.y = f2h(f.y); o.z = f2h(f.z); o.w = f2h(f.w);
        ((ushort4*)xh)[i] = o;
    } else {
        int k = i - n4x;
        if (k >= 2 * n4h) return;
        const float* src = (k < n4h) ? wv : wm;
        int j = (k < n4h) ? k : k - n4h;
        float4 f = ((const float4*)src)[j];
        ushort4 o;
        o.x = f2h(f.x); o.y = f2h(f.y); o.z = f2h(f.z); o.w = f2h(f.w);
        ((ushort4*)wc)[k] = o;
    }
}

// ---- f16 accumulator -> f32 output ----
__global__ void h2f_kernel(const __half2* __restrict__ src, float* __restrict__ dst, int n8) {
    int i = blockIdx.x * blockDim.x + threadIdx.x;
    if (i < n8) {
        float2 a = __half22float2(src[i * 4 + 0]);
        float2 b = __half22float2(src[i * 4 + 1]);
        float2 c = __half22float2(src[i * 4 + 2]);
        float2 d = __half22float2(src[i * 4 + 3]);
        ((float4*)dst)[i * 2 + 0] = make_float4(a.x, a.y, b.x, b.y);
        ((float4*)dst)[i * 2 + 1] = make_float4(c.x, c.y, d.x, d.y);
    }
}

// ---- fused gather + dual-GEMM + softplus*sigmoid + atomic scatter ----
// __launch_bounds__(512,4): caps regs so 2 blocks/CU co-reside (R1: 1 block/CU, 25% occ).
// UseF16: scatter via global_atomic_pk_add_f16 (2 cols/dword-RMW) into f16 scratch —
// halves atomic-op count at the coherent point vs f32 dword atomics (R2: 286 G ops/s,
// suspected fabric RMW ceiling).
template <bool UseF16>
__global__ void __launch_bounds__(THREADS, 4)
cgc_main(const unsigned short* __restrict__ xh,   // [NN][128] f16 bits
         const int* __restrict__ ei,              // [2][E]
         const float* __restrict__ ef,            // [E][64] fp32
         const unsigned short* __restrict__ Wc,   // [256][320] f16 bits
         const float* __restrict__ bval,          // [128]
         const float* __restrict__ bmul,          // [128]
         float* __restrict__ outF,                // [NN][128] fp32 (zeroed)   [!UseF16]
         __half* __restrict__ outH)               // [NN][128] f16  (zeroed)   [UseF16]
{
    __shared__ unsigned short As[BM * SA];    // 18432 B
    __shared__ unsigned short Bs[NTOT * SA];  // 36864 B
    __shared__ int sIdx[BM];
    __shared__ int rIdx[BM];

    const int tid  = threadIdx.x;
    const int e0   = blockIdx.x * BM;
    const int lane = tid & 63;
    const int wid  = tid >> 6;      // 0..7
    const int wm   = wid & 1;       // M half: rows [wm*64, wm*64+64)
    const int wn   = wid >> 1;      // 0..3: N strip of 32 output cols
    const int q    = lane >> 4;     // quad
    const int l16  = lane & 15;

    if (tid < BM) {
        sIdx[tid] = ei[e0 + tid];
        rIdx[tid] = ei[E_EDGES + e0 + tid];
    }

    f32x4 acc[4][4];
    const f32x4 zero4 = {0.f, 0.f, 0.f, 0.f};
#pragma unroll
    for (int mt = 0; mt < 4; ++mt)
#pragma unroll
        for (int nt = 0; nt < 4; ++nt) acc[mt][nt] = zero4;

    for (int c = 0; c < 5; ++c) {
        __syncthreads();   // idx ready (c=0) / prev compute done reading LDS
        // ---- stage A chunk: 128 rows x 64 k (f16) ----
        if (c < 4) {
            const int kcol = (c & 1) * 64;   // column offset within x row
#pragma unroll
            for (int i = 0; i < 2; ++i) {
                int u = tid + i * THREADS;   // 0..1023
                int row = u >> 3, seg = u & 7;
                int node = (c < 2) ? sIdx[row] : rIdx[row];
                uint4 v = *(const uint4*)(xh + (size_t)node * NODE_DIM + kcol + seg * 8);
                *(uint4*)(&As[row * SA + seg * 8]) = v;
            }
        } else {
            // edge_ft: fp32 -> f16 convert on the fly
#pragma unroll
            for (int i = 0; i < 2; ++i) {
                int u = tid + i * THREADS;   // 0..1023 ; 8 floats per unit
                int row = u >> 3, seg = u & 7;
                const float* s = ef + (size_t)(e0 + row) * EDGE_DIM + seg * 8;
                float4 f0 = ((const float4*)s)[0];
                float4 f1 = ((const float4*)s)[1];
                uint4 v;
                v.x = (unsigned)f2h(f0.x) | ((unsigned)f2h(f0.y) << 16);
                v.y = (unsigned)f2h(f0.z) | ((unsigned)f2h(f0.w) << 16);
                v.z = (unsigned)f2h(f1.x) | ((unsigned)f2h(f1.y) << 16);
                v.w = (unsigned)f2h(f1.z) | ((unsigned)f2h(f1.w) << 16);
                *(uint4*)(&As[row * SA + seg * 8]) = v;
            }
        }
        // ---- stage B chunk: 256 rows x 64 k (f16, from L2-resident Wc) ----
        {
            const int kOff = c * BK;
#pragma unroll
            for (int i = 0; i < 4; ++i) {
                int u = tid + i * THREADS;   // 0..2047
                int n = u >> 3, seg = u & 7;
                uint4 v = *(const uint4*)(Wc + n * KDIM + kOff + seg * 8);
                *(uint4*)(&Bs[n * SA + seg * 8]) = v;
            }
        }
        __syncthreads();
        // ---- compute: 2 k-steps x 16 mfma ----
#pragma unroll
        for (int ks = 0; ks < BK; ks += 32) {
            half8 a[4], b[4];
#pragma unroll
            for (int mt = 0; mt < 4; ++mt)
                a[mt] = *(const half8*)(&As[(wm * 64 + mt * 16 + l16) * SA + ks + q * 8]);
            const int nb0 = wn * 32;
            const int nbase[4] = { nb0, nb0 + 16, 128 + nb0, 128 + nb0 + 16 };
#pragma unroll
            for (int nt = 0; nt < 4; ++nt)
                b[nt] = *(const half8*)(&Bs[(nbase[nt] + l16) * SA + ks + q * 8]);
#pragma unroll
            for (int mt = 0; mt < 4; ++mt)
#pragma unroll
                for (int nt = 0; nt < 4; ++nt)
                    acc[mt][nt] = __builtin_amdgcn_mfma_f32_16x16x32_f16(
                        a[mt], b[nt], acc[mt][nt], 0, 0, 0);
        }
    }

    // ---- epilogue: msg = softplus(val+bv) * sigmoid(gate+bm); atomic scatter ----
    // softplus(v) = max(v,0) + log(1+exp(-|v|)); sigmoid(g) = rcp(1+exp(-g))
    // UseF16: pair adjacent cols (adjacent lanes in C/D layout) via shfl_xor(1),
    // even lanes issue one pk_add_f16 covering both -> half the dword RMWs.
#pragma unroll
    for (int ct = 0; ct < 2; ++ct) {
        const int col = wn * 32 + ct * 16 + l16;
        const float bv = bval[col];
        const float bm = bmul[col];
#pragma unroll
        for (int mt = 0; mt < 4; ++mt) {
#pragma unroll
            for (int r = 0; r < 4; ++r) {
                float v = acc[mt][ct][r] + bv;
                float g = acc[mt][ct + 2][r] + bm;
                float sp  = fmaxf(v, 0.f) + __logf(1.f + __expf(-fabsf(v)));
                float sig = __builtin_amdgcn_rcpf(1.f + __expf(-g));
                float msg = sp * sig;
                int rl = wm * 64 + mt * 16 + q * 4 + r;   // local edge row
                int node = rIdx[rl];
                if (UseF16) {
                    float other = __shfl_xor(msg, 1, 64);  // partner col's value
                    if ((l16 & 1) == 0) {
                        __half2 h2;
                        h2.x = __float2half(msg);
                        h2.y = __float2half(other);
                        unsafeAtomicAdd((__half2*)(outH + (size_t)node * NODE_DIM + col), h2);
                    }
                } else {
                    atomicAdd(outF + (size_t)node * NODE_DIM + col, msg);
                }
            }
        }
    }
}

extern "C" void kernel_launch(void* const* d_in, const int* in_sizes, int n_in,
                              void* d_out, int out_size, void* d_ws, size_t ws_size,
                              hipStream_t stream) {
    const float* x  = (const float*)d_in[0];
    const int*   ei = (const int*)d_in[1];
    const float* ef = (const float*)d_in[2];
    const float* Wv = (const float*)d_in[3];
    const float* bv = (const float*)d_in[4];
    const float* Wm = (const float*)d_in[5];
    const float* bm = (const float*)d_in[6];
    float* out = (float*)d_out;

    unsigned short* xh  = (unsigned short*)d_ws;                                 // 12.8 MB
    unsigned short* Wc  = (unsigned short*)((char*)d_ws + 12800000);             // 160 KB
    __half*         mH  = (__half*)((char*)d_ws + 12800000 + 163840);            // 12.8 MB

    const size_t msgBytes = (size_t)NN_NODES * NODE_DIM * sizeof(__half);
    const size_t need = 12800000 + 163840 + msgBytes;
    const bool f16path = (ws_size >= need);

    const int n4x = (NN_NODES * NODE_DIM) / 4;            // 1,600,000
    const int n4w = (2 * NODE_DIM * KDIM) / 4;            // 20,480
    const int total = n4x + n4w;
    cast_all_kernel<<<(total + 255) / 256, 256, 0, stream>>>(x, Wv, Wm, xh, Wc);

    if (f16path) {
        hipMemsetAsync(mH, 0, msgBytes, stream);
        cgc_main<true><<<E_EDGES / BM, THREADS, 0, stream>>>(xh, ei, ef, Wc, bv, bm, nullptr, mH);
        const int n8 = (NN_NODES * NODE_DIM) / 8;         // 800,000
        h2f_kernel<<<(n8 + 255) / 256, 256, 0, stream>>>((const __half2*)mH, out, n8);
    } else {
        hipMemsetAsync(out, 0, (size_t)NN_NODES * NODE_DIM * sizeof(float), stream);
        cgc_main<false><<<E_EDGES / BM, THREADS, 0, stream>>>(xh, ei, ef, Wc, bv, bm, out, nullptr);
    }
}

// Round 4
// 600.875 us; speedup vs baseline: 1.0205x; 1.0205x over previous
//
#include <hip/hip_runtime.h>
#include <hip/hip_bf16.h>

#define E_EDGES   800000
#define NN_NODES  50000
#define NODE_DIM  128
#define EDGE_DIM  64
#define KDIM      320
#define NTOT      256      // val(128) || gate(128)
#define BM        128      // edges per block
#define BK        64       // K chunk
#define THREADS   512

typedef _Float16 half8 __attribute__((ext_vector_type(8)));
typedef float    f32x4 __attribute__((ext_vector_type(4)));

__device__ __forceinline__ unsigned short f2h(float f) {
    _Float16 h = (_Float16)f;
    return __builtin_bit_cast(unsigned short, h);
}

// async global -> LDS, 16 bytes per lane. Dest is wave-uniform base + lane*16;
// our slot layout is exactly lane-ordered so per-lane pointer is safe.
__device__ __forceinline__ void gl_lds16(const void* g, void* l) {
    __builtin_amdgcn_global_load_lds(
        (const __attribute__((address_space(1))) unsigned int*)g,
        (__attribute__((address_space(3))) unsigned int*)l,
        16, 0, 0);
}

// ---- cast x (N_NODES x 128) and W_val||W_mul (256 x 320) fp32 -> f16, one launch ----
__global__ void cast_all_kernel(const float* __restrict__ x,
                                const float* __restrict__ wv,
                                const float* __restrict__ wm,
                                unsigned short* __restrict__ xh,
                                unsigned short* __restrict__ wc) {
    const int n4x = (NN_NODES * NODE_DIM) / 4;        // 1,600,000
    const int n4h = (NODE_DIM * KDIM) / 4;            // 10,240
    int i = blockIdx.x * blockDim.x + threadIdx.x;
    if (i < n4x) {
        float4 f = ((const float4*)x)[i];
        ushort4 o;
        o.x = f2h(f.x); o.y = f2h(f.y); o.z = f2h(f.z); o.w = f2h(f.w);
        ((ushort4*)xh)[i] = o;
    } else {
        int k = i - n4x;
        if (k >= 2 * n4h) return;
        const float* src = (k < n4h) ? wv : wm;
        int j = (k < n4h) ? k : k - n4h;
        float4 f = ((const float4*)src)[j];
        ushort4 o;
        o.x = f2h(f.x); o.y = f2h(f.y); o.z = f2h(f.z); o.w = f2h(f.w);
        ((ushort4*)wc)[k] = o;
    }
}

// ---- fused gather + dual-GEMM + softplus*sigmoid + atomic scatter ----
// Staging via global_load_lds (async DMA, no VGPR round-trip). LDS is unpadded
// (required: dest = wave-uniform base + lane*16); bank conflicts broken by XOR
// swizzle folded into the SOURCE address: mem-segment s of row r lives at slot
// s^(r&7). 8 consecutive lanes then cover all 32 banks (2-way alias = free).
__global__ void __launch_bounds__(THREADS, 4)
cgc_main(const unsigned short* __restrict__ xh,   // [NN][128] f16 bits
         const int* __restrict__ ei,              // [2][E]
         const float* __restrict__ ef,            // [E][64] fp32
         const unsigned short* __restrict__ Wc,   // [256][320] f16 bits
         const float* __restrict__ bval,          // [128]
         const float* __restrict__ bmul,          // [128]
         float* __restrict__ out)                 // [NN][128] fp32 (zeroed)
{
    __shared__ unsigned short As[BM * BK];    // 16384 B, slot u=(row*8+slot)*8 halves
    __shared__ unsigned short Bs[NTOT * BK];  // 32768 B
    __shared__ int sIdx[BM];
    __shared__ int rIdx[BM];

    const int tid  = threadIdx.x;
    const int e0   = blockIdx.x * BM;
    const int lane = tid & 63;
    const int wid  = tid >> 6;      // 0..7
    const int wm   = wid & 1;       // M half: rows [wm*64, wm*64+64)
    const int wn   = wid >> 1;      // 0..3: N strip of 32 output cols
    const int q    = lane >> 4;     // quad
    const int l16  = lane & 15;

    if (tid < BM) {
        sIdx[tid] = ei[e0 + tid];
        rIdx[tid] = ei[E_EDGES + e0 + tid];
    }

    f32x4 acc[4][4];
    const f32x4 zero4 = {0.f, 0.f, 0.f, 0.f};
#pragma unroll
    for (int mt = 0; mt < 4; ++mt)
#pragma unroll
        for (int nt = 0; nt < 4; ++nt) acc[mt][nt] = zero4;

    for (int c = 0; c < 5; ++c) {
        __syncthreads();   // idx ready (c=0) / prev compute done reading LDS
        // ---- stage A chunk: 128 rows x 64 k (f16) ----
        if (c < 4) {
            const int kcol = (c & 1) * 64;           // half-offset within x row
            const int* idx = (c < 2) ? sIdx : rIdx;
#pragma unroll
            for (int i = 0; i < 2; ++i) {
                int u = tid + i * THREADS;           // 0..1023
                int row = u >> 3, sl = u & 7;
                int sm = sl ^ (row & 7);             // swizzled source segment
                int node = idx[row];
                gl_lds16(xh + (size_t)node * NODE_DIM + kcol + sm * 8, &As[u * 8]);
            }
        } else {
            // edge_ft: fp32 -> f16 convert on the fly (manual ds_write, same swizzle)
#pragma unroll
            for (int i = 0; i < 2; ++i) {
                int u = tid + i * THREADS;           // 0..1023 ; 8 floats per unit
                int row = u >> 3, sl = u & 7;
                int sm = sl ^ (row & 7);
                const float* s = ef + (size_t)(e0 + row) * EDGE_DIM + sm * 8;
                float4 f0 = ((const float4*)s)[0];
                float4 f1 = ((const float4*)s)[1];
                uint4 v;
                v.x = (unsigned)f2h(f0.x) | ((unsigned)f2h(f0.y) << 16);
                v.y = (unsigned)f2h(f0.z) | ((unsigned)f2h(f0.w) << 16);
                v.z = (unsigned)f2h(f1.x) | ((unsigned)f2h(f1.y) << 16);
                v.w = (unsigned)f2h(f1.z) | ((unsigned)f2h(f1.w) << 16);
                *(uint4*)(&As[u * 8]) = v;
            }
        }
        // ---- stage B chunk: 256 rows x 64 k (f16, L2-resident Wc) ----
        {
            const int kOff = c * BK;
#pragma unroll
            for (int i = 0; i < 4; ++i) {
                int u = tid + i * THREADS;           // 0..2047
                int n = u >> 3, sl = u & 7;
                int sm = sl ^ (n & 7);
                gl_lds16(Wc + n * KDIM + kOff + sm * 8, &Bs[u * 8]);
            }
        }
        __syncthreads();   // drains vmcnt (global_load_lds) + lgkmcnt
        // ---- compute: 2 k-steps x 16 mfma, swizzled LDS reads ----
#pragma unroll
        for (int ks8 = 0; ks8 < 8; ks8 += 4) {       // 16-B segment index base
            half8 a[4], b[4];
#pragma unroll
            for (int mt = 0; mt < 4; ++mt) {
                int r = wm * 64 + mt * 16 + l16;
                a[mt] = *(const half8*)(&As[r * BK + (((ks8 + q) ^ (r & 7)) << 3)]);
            }
            const int nb0 = wn * 32;
            const int nbase[4] = { nb0, nb0 + 16, 128 + nb0, 128 + nb0 + 16 };
#pragma unroll
            for (int nt = 0; nt < 4; ++nt) {
                int n = nbase[nt] + l16;
                b[nt] = *(const half8*)(&Bs[n * BK + (((ks8 + q) ^ (n & 7)) << 3)]);
            }
#pragma unroll
            for (int mt = 0; mt < 4; ++mt)
#pragma unroll
                for (int nt = 0; nt < 4; ++nt)
                    acc[mt][nt] = __builtin_amdgcn_mfma_f32_16x16x32_f16(
                        a[mt], b[nt], acc[mt][nt], 0, 0, 0);
        }
    }

    // ---- epilogue: msg = softplus(val+bv) * sigmoid(gate+bm); f32 atomic scatter ----
#pragma unroll
    for (int ct = 0; ct < 2; ++ct) {
        const int col = wn * 32 + ct * 16 + l16;
        const float bv = bval[col];
        const float bm = bmul[col];
#pragma unroll
        for (int mt = 0; mt < 4; ++mt) {
#pragma unroll
            for (int r = 0; r < 4; ++r) {
                float v = acc[mt][ct][r] + bv;
                float g = acc[mt][ct + 2][r] + bm;
                float sp  = fmaxf(v, 0.f) + __logf(1.f + __expf(-fabsf(v)));
                float sig = __builtin_amdgcn_rcpf(1.f + __expf(-g));
                float msg = sp * sig;
                int rl = wm * 64 + mt * 16 + q * 4 + r;   // local edge row
                int node = rIdx[rl];
                atomicAdd(out + (size_t)node * NODE_DIM + col, msg);
            }
        }
    }
}

extern "C" void kernel_launch(void* const* d_in, const int* in_sizes, int n_in,
                              void* d_out, int out_size, void* d_ws, size_t ws_size,
                              hipStream_t stream) {
    const float* x  = (const float*)d_in[0];
    const int*   ei = (const int*)d_in[1];
    const float* ef = (const float*)d_in[2];
    const float* Wv = (const float*)d_in[3];
    const float* bv = (const float*)d_in[4];
    const float* Wm = (const float*)d_in[5];
    const float* bm = (const float*)d_in[6];
    float* out = (float*)d_out;

    unsigned short* xh = (unsigned short*)d_ws;                        // 12.8 MB
    unsigned short* Wc = (unsigned short*)((char*)d_ws + 12800000);    // 160 KB

    hipMemsetAsync(d_out, 0, (size_t)NN_NODES * NODE_DIM * sizeof(float), stream);

    const int n4x = (NN_NODES * NODE_DIM) / 4;            // 1,600,000
    const int n4w = (2 * NODE_DIM * KDIM) / 4;            // 20,480
    const int total = n4x + n4w;
    cast_all_kernel<<<(total + 255) / 256, 256, 0, stream>>>(x, Wv, Wm, xh, Wc);

    cgc_main<<<E_EDGES / BM, THREADS, 0, stream>>>(xh, ei, ef, Wc, bv, bm, out);
}